// Round 4
// baseline (391.921 us; speedup 1.0000x reference)
//
#include <hip/hip_runtime.h>
#include <stdint.h>

#define BM 128
#define BN 128
#define BK 64
#define TILE_ELEMS (128 * 64)  // one 128x64 f16 tile in LDS

typedef _Float16 f16;
typedef __attribute__((ext_vector_type(8))) _Float16 f16x8;
typedef __attribute__((ext_vector_type(4))) _Float16 f16x4;
typedef __attribute__((ext_vector_type(4))) float floatx4;

static __device__ __forceinline__ void async_load16(const void* g, void* l) {
    __builtin_amdgcn_global_load_lds(
        (const __attribute__((address_space(1))) unsigned int*)g,
        (__attribute__((address_space(3))) unsigned int*)l, 16, 0, 0);
}

// Stage a 128x64 f16 tile from global (row-major, ld elements) into LDS.
// LDS layout: linear [128 row][8 chunk][8 f16], where chunk ck of row r holds
// global chunk (ck ^ (r&7)) of row r  (XOR swizzle, both-sides-or-neither:
// inverse-swizzled SOURCE + linear gload_lds dest + swizzled ds_read).
static __device__ __forceinline__ void stage_tile(const f16* src, int ld, f16* lds, int tid) {
    int lane = tid & 63;
    int wbase = (tid >> 6) * 64;
#pragma unroll
    for (int t = 0; t < 4; ++t) {
        int c = wbase + t * 256 + lane;
        int r = c >> 3, ck = c & 7;
        const f16* gp = src + (size_t)r * ld + ((ck ^ (r & 7)) << 3);
        f16* lp = lds + (size_t)(wbase + t * 256) * 8;  // wave-uniform; HW adds lane*16B
        async_load16(gp, lp);
    }
}

// Same tile + layout, but source is fp32: reg-stage (2x float4), convert to
// f16x8, ds_write_b128. Per-lane LDS scatter is fine for ds_write, so the
// destination is the linear chunk index; source uses the inverse swizzle.
static __device__ __forceinline__ void stage_tile_f32(const float* src, int ld, f16* lds, int tid) {
#pragma unroll
    for (int t = 0; t < 4; ++t) {
        int c = t * 256 + tid;  // chunk 0..1023
        int r = c >> 3, ck = c & 7;
        const float* gp = src + (size_t)r * ld + ((ck ^ (r & 7)) << 3);
        float4 lo = *(const float4*)gp;
        float4 hi = *(const float4*)(gp + 4);
        f16x8 h = {(f16)lo.x, (f16)lo.y, (f16)lo.z, (f16)lo.w,
                   (f16)hi.x, (f16)hi.y, (f16)hi.z, (f16)hi.w};
        *(f16x8*)(lds + (size_t)c * 8) = h;
    }
}

static __device__ __forceinline__ f16x8 frag(const f16* lds, int row, int kblk) {
    // chunk (kblk ^ (row&7)) holds global k-chunk kblk of this row
    return *(const f16x8*)(lds + (((row << 3) + (kblk ^ (row & 7))) << 3));
}

// CMODE: 0 = fp32 out (+bias), 1 = f16 out (+bias), 3 = f16 transposed vT out (+bias)
// AF32: A operand is fp32 in global, converted during staging.
template <int CMODE, bool AF32>
static __device__ __forceinline__ void gemm_body(
    f16* As, f16* Bs,
    const void* Ap, int lda, long long a_zoff,
    const f16* Bp, int ldb, long long b_zoff,
    void* Cp, int ldc, long long c_zoff,
    const float* bias, int K, int z)
{
    int tid = threadIdx.x;
    int lane = tid & 63;
    int wid = tid >> 6;
    int wm = wid >> 1, wn = wid & 1;

    // XCD-aware block swizzle (T1); all grids here have (gx*gy)%8==0.
    int gx = gridDim.x;
    int nwg = gx * gridDim.y;
    int bid = blockIdx.y * gx + blockIdx.x;
    if ((nwg & 7) == 0) {
        int chunk = nwg >> 3;
        bid = (bid & 7) * chunk + (bid >> 3);
    }
    int bx = bid % gx;
    int by = bid / gx;

    size_t row0 = (size_t)by * BM;
    size_t col0 = (size_t)bx * BN;

    floatx4 acc[4][4];
#pragma unroll
    for (int i = 0; i < 4; ++i)
#pragma unroll
        for (int j = 0; j < 4; ++j) acc[i][j] = floatx4{0.f, 0.f, 0.f, 0.f};

    const f16* a0h = nullptr;
    const float* a0f = nullptr;
    if constexpr (AF32)
        a0f = (const float*)Ap + (size_t)z * a_zoff + row0 * lda;
    else
        a0h = (const f16*)Ap + (size_t)z * a_zoff + row0 * lda;
    const f16* b0 = Bp + (size_t)z * b_zoff + col0 * ldb;

    int quad = lane >> 4, mr = lane & 15;

    for (int k0 = 0; k0 < K; k0 += BK) {
        __syncthreads();
        if constexpr (AF32)
            stage_tile_f32(a0f + k0, lda, As, tid);
        else
            stage_tile(a0h + k0, lda, As, tid);
        stage_tile(b0 + k0, ldb, Bs, tid);
        __syncthreads();

#pragma unroll
        for (int s = 0; s < 2; ++s) {
            f16x8 ah[4];
#pragma unroll
            for (int i = 0; i < 4; ++i) ah[i] = frag(As, wm * 64 + i * 16 + mr, s * 4 + quad);
#pragma unroll
            for (int j = 0; j < 4; ++j) {
                f16x8 bh = frag(Bs, wn * 64 + j * 16 + mr, s * 4 + quad);
#pragma unroll
                for (int i = 0; i < 4; ++i)
                    acc[i][j] = __builtin_amdgcn_mfma_f32_16x16x32_f16(ah[i], bh, acc[i][j], 0, 0, 0);
            }
        }
    }

#pragma unroll
    for (int i = 0; i < 4; ++i) {
#pragma unroll
        for (int j = 0; j < 4; ++j) {
#pragma unroll
            for (int r = 0; r < 4; ++r) {
                size_t rr = row0 + (size_t)(wm * 64 + i * 16 + quad * 4 + r);
                size_t cc = col0 + (size_t)(wn * 64 + j * 16 + mr);
                float v = acc[i][j][r];
                if (bias) v += bias[cc];
                if constexpr (CMODE == 0) {
                    float* C = (float*)Cp + (size_t)z * c_zoff;
                    C[rr * ldc + cc] = v;
                } else if constexpr (CMODE == 1) {
                    f16* C = (f16*)Cp + (size_t)z * c_zoff;
                    C[rr * ldc + cc] = (f16)v;
                } else {  // vT[b][col][s]: b = rr>>11, s = rr&2047, col dim 1024
                    f16* C = (f16*)Cp;
                    size_t b = rr >> 11, s = rr & 2047;
                    C[((b << 10) + cc) * 2048 + s] = (f16)v;
                }
            }
        }
    }
}

#define DECL_SMEM                                        \
    __shared__ __align__(16) f16 smem[2 * TILE_ELEMS];   \
    f16* As = smem;                                      \
    f16* Bs = smem + TILE_ELEMS;

// Merged q/k/v projection reading the ORIGINAL fp32 inputs (conversion fused
// into A-staging): z selects input tensor, weight, bias, output mode.
__global__ __launch_bounds__(256, 2) void g_qkv(const float* q, const float* k, const float* v,
                                                const f16* W, f16* qk, f16* vT,
                                                const float* bq, const float* bk,
                                                const float* bv, int D, long long ten) {
    DECL_SMEM
    int z = blockIdx.z;
    const float* bias = (z == 0) ? bq : (z == 1) ? bk : bv;
    const float* A = (z == 0) ? q : (z == 1) ? k : v;
    if (z < 2) {
        gemm_body<1, true>(As, Bs, A, D, 0, W + (size_t)z * D * D, D, 0,
                           qk + (size_t)z * ten, D, 0, bias, D, 0);
    } else {
        gemm_body<3, true>(As, Bs, A, D, 0, W + (size_t)2 * D * D, D, 0,
                           vT, 0, 0, bias, D, 0);
    }
}
__global__ __launch_bounds__(256, 2) void g_scores(const f16* A, int lda, long long az,
                                                   const f16* B, int ldb, long long bz,
                                                   float* C, int ldc, long long cz, int K) {
    DECL_SMEM
    gemm_body<0, false>(As, Bs, A, lda, az, B, ldb, bz, C, ldc, cz, nullptr, K, blockIdx.z);
}
__global__ __launch_bounds__(256, 2) void g_attnv(const f16* A, int lda, long long az,
                                                  const f16* B, int ldb, long long bz,
                                                  f16* C, int ldc, long long cz, int K) {
    DECL_SMEM
    gemm_body<1, false>(As, Bs, A, lda, az, B, ldb, bz, C, ldc, cz, nullptr, K, blockIdx.z);
}
__global__ __launch_bounds__(256, 2) void g_out(const f16* A, int lda, const f16* B, int ldb,
                                                float* C, int ldc, const float* bias, int K) {
    DECL_SMEM
    gemm_body<0, false>(As, Bs, A, lda, 0, B, ldb, 0, C, ldc, 0, bias, K, 0);
}

// All four weight transposes in one dispatch; T = [WqT|WkT|WvT|WdT] contiguous.
__global__ __launch_bounds__(256) void wtrans(const float* Wq, const float* Wk,
                                              const float* Wv, const float* Wd,
                                              f16* T, int n) {
    __shared__ float tile[32][33];
    int z = blockIdx.z;
    const float* W = (z == 0) ? Wq : (z == 1) ? Wk : (z == 2) ? Wv : Wd;
    f16* Tz = T + (size_t)z * n * n;
    int bx = blockIdx.x * 32;
    int by = blockIdx.y * 32;
    int tx = threadIdx.x & 31;
    int ty = threadIdx.x >> 5;
    for (int r = ty; r < 32; r += 8) tile[r][tx] = W[(size_t)(by + r) * n + bx + tx];
    __syncthreads();
    for (int r = ty; r < 32; r += 8) Tz[(size_t)(bx + r) * n + by + tx] = (f16)tile[tx][r];
}

// One block per row of 2048 fp32 logits; writes fp16 attn into the first half
// of the same row's storage (row byte stride stays 8192 => f16 lda 4096).
// Vectorized: each thread owns 8 contiguous elements (2x float4 in, 16B out).
__global__ __launch_bounds__(256) void softmax_k(float* scores) {
    size_t row = blockIdx.x;
    float* rp = scores + row * 2048;
    int tid = threadIdx.x;
    int lane = tid & 63, w = tid >> 6;
    const float4* rp4 = (const float4*)(rp + (size_t)tid * 8);
    float4 a = rp4[0], b = rp4[1];
    float x[8] = {a.x, a.y, a.z, a.w, b.x, b.y, b.z, b.w};
    float mx = -3.4e38f;
#pragma unroll
    for (int i = 0; i < 8; ++i) mx = fmaxf(mx, x[i]);
#pragma unroll
    for (int o = 32; o > 0; o >>= 1) mx = fmaxf(mx, __shfl_xor(mx, o, 64));
    __shared__ float redm[4];
    __shared__ float reds[4];
    if (lane == 0) redm[w] = mx;
    __syncthreads();  // also orders: all row reads complete before any write below
    mx = fmaxf(fmaxf(redm[0], redm[1]), fmaxf(redm[2], redm[3]));
    float s = 0.f;
#pragma unroll
    for (int i = 0; i < 8; ++i) {
        x[i] = __expf(x[i] - mx);
        s += x[i];
    }
#pragma unroll
    for (int o = 32; o > 0; o >>= 1) s += __shfl_xor(s, o, 64);
    if (lane == 0) reds[w] = s;
    __syncthreads();
    s = reds[0] + reds[1] + reds[2] + reds[3];
    float inv = 1.f / s;
    f16* op = (f16*)rp + (size_t)tid * 8;
    f16x4 h0 = {(f16)(x[0] * inv), (f16)(x[1] * inv), (f16)(x[2] * inv), (f16)(x[3] * inv)};
    f16x4 h1 = {(f16)(x[4] * inv), (f16)(x[5] * inv), (f16)(x[6] * inv), (f16)(x[7] * inv)};
    *(f16x4*)op = h0;
    *(f16x4*)(op + 4) = h1;
}

extern "C" void kernel_launch(void* const* d_in, const int* in_sizes, int n_in,
                              void* d_out, int out_size, void* d_ws, size_t ws_size,
                              hipStream_t stream) {
    const float* query  = (const float*)d_in[0];
    const float* keys   = (const float*)d_in[1];
    const float* values = (const float*)d_in[2];
    const float* Wq = (const float*)d_in[3];
    const float* bq = (const float*)d_in[4];
    const float* Wk = (const float*)d_in[5];
    const float* bk = (const float*)d_in[6];
    const float* Wv = (const float*)d_in[7];
    const float* bv = (const float*)d_in[8];
    const float* Wd = (const float*)d_in[9];
    const float* bd = (const float*)d_in[10];
    float* out = (float*)d_out;

    const int S = 2048, D = 1024, NB = 4;
    const size_t TEN = (size_t)NB * S * D;  // 8.39M

    char* p = (char*)d_ws;
    auto alloc = [&](size_t bytes) {
        char* r = p;
        p += (bytes + 255) & ~(size_t)255;
        return r;
    };
    f16* q16 = (f16*)alloc(TEN * 2 * 2);   // [q16|k16]
    f16* k16 = q16 + TEN;
    f16* vT  = (f16*)alloc(TEN * 2);
    f16* att = (f16*)alloc(TEN * 2);
    f16* WT  = (f16*)alloc((size_t)D * D * 2 * 4);  // [WqT|WkT|WvT|WdT]
    float* scores = (float*)p;
    long long avail = (long long)ws_size - (long long)(p - (char*)d_ws);
    long long sbytes = (long long)S * S * 4;
    int g = (avail >= 4 * sbytes) ? 4 : (avail >= 2 * sbytes) ? 2 : 1;

    dim3 blk(256);
    wtrans<<<dim3(D / 32, D / 32, 4), blk, 0, stream>>>(Wq, Wk, Wv, Wd, WT, D);

    g_qkv<<<dim3(D / BN, (NB * S) / BM, 3), blk, 0, stream>>>(
        query, keys, values, WT, q16, vT, bq, bk, bv, D, (long long)TEN);

    for (int g0 = 0; g0 < NB; g0 += g) {
        int gz = (NB - g0 < g) ? (NB - g0) : g;
        dim3 sgrid(S / BN, S / BM, gz);  // (16,16,gz)
        g_scores<<<sgrid, blk, 0, stream>>>(
            q16 + (size_t)g0 * S * D, D, (long long)S * D,
            k16 + (size_t)g0 * S * D, D, (long long)S * D,
            scores, S, (long long)S * S, D);
        softmax_k<<<dim3((unsigned)(gz * S)), blk, 0, stream>>>(scores);
        dim3 agrid(D / BN, S / BM, gz);  // (8,16,gz)
        g_attnv<<<agrid, blk, 0, stream>>>(
            (const f16*)scores, 2 * S, (long long)S * 2 * S,
            vT + (size_t)g0 * D * S, S, (long long)D * S,
            att + (size_t)g0 * S * D, D, (long long)S * D, S);
    }

    g_out<<<dim3(D / BN, (NB * S) / BM, 1), blk, 0, stream>>>(att, D, WT + (size_t)3 * D * D, D,
                                                              out, D, bd, D);
}

// Round 5
// 374.314 us; speedup vs baseline: 1.0470x; 1.0470x over previous
//
#include <hip/hip_runtime.h>
#include <stdint.h>

#define BM 128
#define BN 128
#define BK 64
#define TILE_ELEMS (128 * 64)  // one 128x64 f16 tile (16 KB)

typedef _Float16 f16;
typedef __attribute__((ext_vector_type(8))) _Float16 f16x8;
typedef __attribute__((ext_vector_type(4))) _Float16 f16x4;
typedef __attribute__((ext_vector_type(4))) float floatx4;

static __device__ __forceinline__ void async_load16(const void* g, void* l) {
    __builtin_amdgcn_global_load_lds(
        (const __attribute__((address_space(1))) unsigned int*)g,
        (__attribute__((address_space(3))) unsigned int*)l, 16, 0, 0);
}

// Stage a 128x64 f16 tile from global (row-major, ld elements) into LDS.
// LDS layout: linear [128 row][8 chunk][8 f16], where chunk ck of row r holds
// global chunk (ck ^ (r&7)) of row r  (XOR swizzle, both-sides-or-neither:
// inverse-swizzled SOURCE + linear gload_lds dest + swizzled ds_read).
static __device__ __forceinline__ void stage_tile(const f16* src, int ld, f16* lds, int tid) {
    int lane = tid & 63;
    int wbase = (tid >> 6) * 64;
#pragma unroll
    for (int t = 0; t < 4; ++t) {
        int c = wbase + t * 256 + lane;
        int r = c >> 3, ck = c & 7;
        const f16* gp = src + (size_t)r * ld + ((ck ^ (r & 7)) << 3);
        f16* lp = lds + (size_t)(wbase + t * 256) * 8;  // wave-uniform; HW adds lane*16B
        async_load16(gp, lp);
    }
}

static __device__ __forceinline__ f16x8 frag(const f16* lds, int row, int kblk) {
    // chunk (kblk ^ (row&7)) holds global k-chunk kblk of this row
    return *(const f16x8*)(lds + (((row << 3) + (kblk ^ (row & 7))) << 3));
}

// CMODE: 0 = fp32 out (+bias), 1 = f16 out (+bias), 3 = f16 transposed vT out (+bias)
// Double-buffered LDS, stage-before-compute, ONE __syncthreads per K-step:
// the barrier's implicit vmcnt(0) drain lands ~a full compute phase after the
// loads were issued, so HBM latency hides under the 32 MFMAs (T3 min-2-phase).
template <int CMODE>
static __device__ __forceinline__ void gemm_body(
    f16* smem,  // 4 * TILE_ELEMS: [As0|Bs0|As1|Bs1]
    const f16* Ap, int lda, long long a_zoff,
    const f16* Bp, int ldb, long long b_zoff,
    void* Cp, int ldc, long long c_zoff,
    const float* bias, int K, int z)
{
    int tid = threadIdx.x;
    int lane = tid & 63;
    int wid = tid >> 6;
    int wm = wid >> 1, wn = wid & 1;

    // XCD-aware block swizzle (T1); all grids here have (gx*gy)%8==0.
    int gx = gridDim.x;
    int nwg = gx * gridDim.y;
    int bid = blockIdx.y * gx + blockIdx.x;
    if ((nwg & 7) == 0) {
        int chunk = nwg >> 3;
        bid = (bid & 7) * chunk + (bid >> 3);
    }
    int bx = bid % gx;
    int by = bid / gx;

    size_t row0 = (size_t)by * BM;
    size_t col0 = (size_t)bx * BN;

    floatx4 acc[4][4];
#pragma unroll
    for (int i = 0; i < 4; ++i)
#pragma unroll
        for (int j = 0; j < 4; ++j) acc[i][j] = floatx4{0.f, 0.f, 0.f, 0.f};

    const f16* a0 = Ap + (size_t)z * a_zoff + row0 * lda;
    const f16* b0 = Bp + (size_t)z * b_zoff + col0 * ldb;

    int quad = lane >> 4, mr = lane & 15;

    // Prologue: stage K-tile 0 into buffer 0; barrier drains it.
    stage_tile(a0, lda, smem, tid);
    stage_tile(b0, ldb, smem + TILE_ELEMS, tid);
    __syncthreads();

    int kt = 0;
    for (int k0 = 0; k0 < K; k0 += BK, ++kt) {
        f16* Ac = smem + (kt & 1) * (2 * TILE_ELEMS);
        f16* Bc = Ac + TILE_ELEMS;
        if (k0 + BK < K) {
            // Issue next tile's stages BEFORE compute: they fly during the MFMAs.
            f16* An = smem + ((kt & 1) ^ 1) * (2 * TILE_ELEMS);
            stage_tile(a0 + k0 + BK, lda, An, tid);
            stage_tile(b0 + k0 + BK, ldb, An + TILE_ELEMS, tid);
        }

#pragma unroll
        for (int s = 0; s < 2; ++s) {
            f16x8 ah[4];
#pragma unroll
            for (int i = 0; i < 4; ++i) ah[i] = frag(Ac, wm * 64 + i * 16 + mr, s * 4 + quad);
#pragma unroll
            for (int j = 0; j < 4; ++j) {
                f16x8 bh = frag(Bc, wn * 64 + j * 16 + mr, s * 4 + quad);
#pragma unroll
                for (int i = 0; i < 4; ++i)
                    acc[i][j] = __builtin_amdgcn_mfma_f32_16x16x32_f16(ah[i], bh, acc[i][j], 0, 0, 0);
            }
        }
        // Single barrier: drains next tile's loads (issued a compute-phase ago)
        // and protects buffer reuse (iter kt+2 overwrites buf cur only after this).
        __syncthreads();
    }

#pragma unroll
    for (int i = 0; i < 4; ++i) {
#pragma unroll
        for (int j = 0; j < 4; ++j) {
#pragma unroll
            for (int r = 0; r < 4; ++r) {
                size_t rr = row0 + (size_t)(wm * 64 + i * 16 + quad * 4 + r);
                size_t cc = col0 + (size_t)(wn * 64 + j * 16 + mr);
                float v = acc[i][j][r];
                if (bias) v += bias[cc];
                if constexpr (CMODE == 0) {
                    float* C = (float*)Cp + (size_t)z * c_zoff;
                    C[rr * ldc + cc] = v;
                } else if constexpr (CMODE == 1) {
                    f16* C = (f16*)Cp + (size_t)z * c_zoff;
                    C[rr * ldc + cc] = (f16)v;
                } else {  // vT[b][col][s]: b = rr>>11, s = rr&2047, col dim 1024
                    f16* C = (f16*)Cp;
                    size_t b = rr >> 11, s = rr & 2047;
                    C[((b << 10) + cc) * 2048 + s] = (f16)v;
                }
            }
        }
    }
}

#define DECL_SMEM __shared__ __align__(16) f16 smem[4 * TILE_ELEMS];

// Merged q/k/v projection: z selects input tensor, weight, bias, output mode.
// x = [xq|xk|xv] contiguous, W = [WqT|WkT|WvT] contiguous, qk = [q16|k16] contiguous.
__global__ __launch_bounds__(256, 2) void g_qkv(const f16* x, const f16* W,
                                                f16* qk, f16* vT,
                                                const float* bq, const float* bk,
                                                const float* bv, int D, long long ten) {
    DECL_SMEM
    int z = blockIdx.z;
    const float* bias = (z == 0) ? bq : (z == 1) ? bk : bv;
    if (z < 2) {
        gemm_body<1>(smem, x + (size_t)z * ten, D, 0, W + (size_t)z * D * D, D, 0,
                     qk + (size_t)z * ten, D, 0, bias, D, 0);
    } else {
        gemm_body<3>(smem, x + (size_t)2 * ten, D, 0, W + (size_t)2 * D * D, D, 0,
                     vT, 0, 0, bias, D, 0);
    }
}
__global__ __launch_bounds__(256, 2) void g_scores(const f16* A, int lda, long long az,
                                                   const f16* B, int ldb, long long bz,
                                                   float* C, int ldc, long long cz, int K) {
    DECL_SMEM
    gemm_body<0>(smem, A, lda, az, B, ldb, bz, C, ldc, cz, nullptr, K, blockIdx.z);
}
__global__ __launch_bounds__(256, 2) void g_attnv(const f16* A, int lda, long long az,
                                                  const f16* B, int ldb, long long bz,
                                                  f16* C, int ldc, long long cz, int K) {
    DECL_SMEM
    gemm_body<1>(smem, A, lda, az, B, ldb, bz, C, ldc, cz, nullptr, K, blockIdx.z);
}
__global__ __launch_bounds__(256, 2) void g_out(const f16* A, int lda, const f16* B, int ldb,
                                                float* C, int ldc, const float* bias, int K) {
    DECL_SMEM
    gemm_body<0>(smem, A, lda, 0, B, ldb, 0, C, ldc, 0, bias, K, 0);
}

// fp32 -> fp16 convert for q/k/v in one dispatch; dst = [xq|xk|xv] contiguous.
__global__ __launch_bounds__(256) void cvt_f16(const float* q, const float* k, const float* v,
                                               f16* dst, long long ten) {
    int z = blockIdx.y;
    const float* src = (z == 0) ? q : (z == 1) ? k : v;
    size_t i = ((size_t)blockIdx.x * 256 + threadIdx.x) * 4;
    float4 x = *(const float4*)(src + i);
    f16x4 h = {(f16)x.x, (f16)x.y, (f16)x.z, (f16)x.w};
    *(f16x4*)(dst + (size_t)z * ten + i) = h;
}

// All four weight transposes in one dispatch; T = [WqT|WkT|WvT|WdT] contiguous.
__global__ __launch_bounds__(256) void wtrans(const float* Wq, const float* Wk,
                                              const float* Wv, const float* Wd,
                                              f16* T, int n) {
    __shared__ float tile[32][33];
    int z = blockIdx.z;
    const float* W = (z == 0) ? Wq : (z == 1) ? Wk : (z == 2) ? Wv : Wd;
    f16* Tz = T + (size_t)z * n * n;
    int bx = blockIdx.x * 32;
    int by = blockIdx.y * 32;
    int tx = threadIdx.x & 31;
    int ty = threadIdx.x >> 5;
    for (int r = ty; r < 32; r += 8) tile[r][tx] = W[(size_t)(by + r) * n + bx + tx];
    __syncthreads();
    for (int r = ty; r < 32; r += 8) Tz[(size_t)(bx + r) * n + by + tx] = (f16)tile[tx][r];
}

// One block per row of 2048 fp32 logits; writes fp16 attn into the first half
// of the same row's storage (row byte stride stays 8192 => f16 lda 4096).
// Vectorized: each thread owns 8 contiguous elements (2x float4 in, 16B out).
__global__ __launch_bounds__(256) void softmax_k(float* scores) {
    size_t row = blockIdx.x;
    float* rp = scores + row * 2048;
    int tid = threadIdx.x;
    int lane = tid & 63, w = tid >> 6;
    const float4* rp4 = (const float4*)(rp + (size_t)tid * 8);
    float4 a = rp4[0], b = rp4[1];
    float x[8] = {a.x, a.y, a.z, a.w, b.x, b.y, b.z, b.w};
    float mx = -3.4e38f;
#pragma unroll
    for (int i = 0; i < 8; ++i) mx = fmaxf(mx, x[i]);
#pragma unroll
    for (int o = 32; o > 0; o >>= 1) mx = fmaxf(mx, __shfl_xor(mx, o, 64));
    __shared__ float redm[4];
    __shared__ float reds[4];
    if (lane == 0) redm[w] = mx;
    __syncthreads();  // also orders: all row reads complete before any write below
    mx = fmaxf(fmaxf(redm[0], redm[1]), fmaxf(redm[2], redm[3]));
    float s = 0.f;
#pragma unroll
    for (int i = 0; i < 8; ++i) {
        x[i] = __expf(x[i] - mx);
        s += x[i];
    }
#pragma unroll
    for (int o = 32; o > 0; o >>= 1) s += __shfl_xor(s, o, 64);
    if (lane == 0) reds[w] = s;
    __syncthreads();
    s = reds[0] + reds[1] + reds[2] + reds[3];
    float inv = 1.f / s;
    f16* op = (f16*)rp + (size_t)tid * 8;
    f16x4 h0 = {(f16)(x[0] * inv), (f16)(x[1] * inv), (f16)(x[2] * inv), (f16)(x[3] * inv)};
    f16x4 h1 = {(f16)(x[4] * inv), (f16)(x[5] * inv), (f16)(x[6] * inv), (f16)(x[7] * inv)};
    *(f16x4*)op = h0;
    *(f16x4*)(op + 4) = h1;
}

extern "C" void kernel_launch(void* const* d_in, const int* in_sizes, int n_in,
                              void* d_out, int out_size, void* d_ws, size_t ws_size,
                              hipStream_t stream) {
    const float* query  = (const float*)d_in[0];
    const float* keys   = (const float*)d_in[1];
    const float* values = (const float*)d_in[2];
    const float* Wq = (const float*)d_in[3];
    const float* bq = (const float*)d_in[4];
    const float* Wk = (const float*)d_in[5];
    const float* bk = (const float*)d_in[6];
    const float* Wv = (const float*)d_in[7];
    const float* bv = (const float*)d_in[8];
    const float* Wd = (const float*)d_in[9];
    const float* bd = (const float*)d_in[10];
    float* out = (float*)d_out;

    const int S = 2048, D = 1024, NB = 4;
    const size_t TEN = (size_t)NB * S * D;  // 8.39M, TEN*2 bytes is 256-aligned

    char* p = (char*)d_ws;
    auto alloc = [&](size_t bytes) {
        char* r = p;
        p += (bytes + 255) & ~(size_t)255;
        return r;
    };
    f16* x3  = (f16*)alloc(TEN * 2 * 3);   // [xq|xk|xv]
    f16* q16 = (f16*)alloc(TEN * 2 * 2);   // [q16|k16]
    f16* k16 = q16 + TEN;
    f16* vT  = (f16*)alloc(TEN * 2);
    f16* WT  = (f16*)alloc((size_t)D * D * 2 * 4);  // [WqT|WkT|WvT|WdT]
    float* scores = (float*)p;
    long long avail = (long long)ws_size - (long long)(p - (char*)d_ws);
    long long sbytes = (long long)S * S * 4;
    int g = (avail >= 4 * sbytes) ? 4 : (avail >= 2 * sbytes) ? 2 : 1;
    f16* att = x3;  // alias: x3 is dead after the qkv projections

    dim3 blk(256);
    cvt_f16<<<dim3((unsigned)(TEN / 1024), 3), blk, 0, stream>>>(query, keys, values, x3, TEN);
    wtrans<<<dim3(D / 32, D / 32, 4), blk, 0, stream>>>(Wq, Wk, Wv, Wd, WT, D);

    g_qkv<<<dim3(D / BN, (NB * S) / BM, 3), blk, 0, stream>>>(
        x3, WT, q16, vT, bq, bk, bv, D, (long long)TEN);

    for (int g0 = 0; g0 < NB; g0 += g) {
        int gz = (NB - g0 < g) ? (NB - g0) : g;
        dim3 sgrid(S / BN, S / BM, gz);  // (16,16,gz)
        g_scores<<<sgrid, blk, 0, stream>>>(
            q16 + (size_t)g0 * S * D, D, (long long)S * D,
            k16 + (size_t)g0 * S * D, D, (long long)S * D,
            scores, S, (long long)S * S, D);
        softmax_k<<<dim3((unsigned)(gz * S)), blk, 0, stream>>>(scores);
        dim3 agrid(D / BN, S / BM, gz);  // (8,16,gz)
        g_attnv<<<agrid, blk, 0, stream>>>(
            (const f16*)scores, 2 * S, (long long)S * 2 * S,
            vT + (size_t)g0 * D * S, S, (long long)D * S,
            att + (size_t)g0 * S * D, D, (long long)S * D, S);
    }

    g_out<<<dim3(D / BN, (NB * S) / BM, 1), blk, 0, stream>>>(att, D, WT + (size_t)3 * D * D, D,
                                                              out, D, bd, D);
}

// Round 6
// 352.811 us; speedup vs baseline: 1.1109x; 1.0609x over previous
//
#include <hip/hip_runtime.h>
#include <stdint.h>

#define BM 128
#define BN 128
#define BK 64
#define TILE_ELEMS (128 * 64)  // one 128x64 f16 tile in LDS

typedef _Float16 f16;
typedef __attribute__((ext_vector_type(8))) _Float16 f16x8;
typedef __attribute__((ext_vector_type(4))) _Float16 f16x4;
typedef __attribute__((ext_vector_type(4))) float floatx4;

static __device__ __forceinline__ void async_load16(const void* g, void* l) {
    __builtin_amdgcn_global_load_lds(
        (const __attribute__((address_space(1))) unsigned int*)g,
        (__attribute__((address_space(3))) unsigned int*)l, 16, 0, 0);
}

// Stage a 128x64 f16 tile from global (row-major, ld elements) into LDS.
// LDS layout: linear [128 row][8 chunk][8 f16], where chunk ck of row r holds
// global chunk (ck ^ (r&7)) of row r  (XOR swizzle, both-sides-or-neither:
// inverse-swizzled SOURCE + linear gload_lds dest + swizzled ds_read).
// Lane order = consecutive 16B chunks => wave reads 8 contiguous 128B rows.
static __device__ __forceinline__ void stage_tile(const f16* src, int ld, f16* lds, int tid) {
    int lane = tid & 63;
    int wbase = (tid >> 6) * 64;
#pragma unroll
    for (int t = 0; t < 4; ++t) {
        int c = wbase + t * 256 + lane;
        int r = c >> 3, ck = c & 7;
        const f16* gp = src + (size_t)r * ld + ((ck ^ (r & 7)) << 3);
        f16* lp = lds + (size_t)(wbase + t * 256) * 8;  // wave-uniform; HW adds lane*16B
        async_load16(gp, lp);
    }
}

static __device__ __forceinline__ f16x8 frag(const f16* lds, int row, int kblk) {
    // chunk (kblk ^ (row&7)) holds global k-chunk kblk of this row
    return *(const f16x8*)(lds + (((row << 3) + (kblk ^ (row & 7))) << 3));
}

// CMODE: 0 = fp32 out (+bias), 1 = f16 out (+bias), 3 = f16 transposed vT out (+bias)
// Shared memory is passed in so multiple instantiations in one kernel share it.
template <int CMODE>
static __device__ __forceinline__ void gemm_body(
    f16* As, f16* Bs,
    const f16* Ap, int lda, long long a_zoff,
    const f16* Bp, int ldb, long long b_zoff,
    void* Cp, int ldc, long long c_zoff,
    const float* bias, int K, int z)
{
    int tid = threadIdx.x;
    int lane = tid & 63;
    int wid = tid >> 6;
    int wm = wid >> 1, wn = wid & 1;

    // XCD-aware block swizzle (T1); all grids here have (gx*gy)%8==0.
    int gx = gridDim.x;
    int nwg = gx * gridDim.y;
    int bid = blockIdx.y * gx + blockIdx.x;
    if ((nwg & 7) == 0) {
        int chunk = nwg >> 3;
        bid = (bid & 7) * chunk + (bid >> 3);
    }
    int bx = bid % gx;
    int by = bid / gx;

    size_t row0 = (size_t)by * BM;
    size_t col0 = (size_t)bx * BN;

    floatx4 acc[4][4];
#pragma unroll
    for (int i = 0; i < 4; ++i)
#pragma unroll
        for (int j = 0; j < 4; ++j) acc[i][j] = floatx4{0.f, 0.f, 0.f, 0.f};

    const f16* a0 = Ap + (size_t)z * a_zoff + row0 * lda;
    const f16* b0 = Bp + (size_t)z * b_zoff + col0 * ldb;

    int quad = lane >> 4, mr = lane & 15;

    for (int k0 = 0; k0 < K; k0 += BK) {
        __syncthreads();
        stage_tile(a0 + k0, lda, As, tid);
        stage_tile(b0 + k0, ldb, Bs, tid);
        __syncthreads();

#pragma unroll
        for (int s = 0; s < 2; ++s) {
            f16x8 ah[4];
#pragma unroll
            for (int i = 0; i < 4; ++i) ah[i] = frag(As, wm * 64 + i * 16 + mr, s * 4 + quad);
#pragma unroll
            for (int j = 0; j < 4; ++j) {
                f16x8 bh = frag(Bs, wn * 64 + j * 16 + mr, s * 4 + quad);
#pragma unroll
                for (int i = 0; i < 4; ++i)
                    acc[i][j] = __builtin_amdgcn_mfma_f32_16x16x32_f16(ah[i], bh, acc[i][j], 0, 0, 0);
            }
        }
    }

#pragma unroll
    for (int i = 0; i < 4; ++i) {
#pragma unroll
        for (int j = 0; j < 4; ++j) {
#pragma unroll
            for (int r = 0; r < 4; ++r) {
                size_t rr = row0 + (size_t)(wm * 64 + i * 16 + quad * 4 + r);
                size_t cc = col0 + (size_t)(wn * 64 + j * 16 + mr);
                float v = acc[i][j][r];
                if (bias) v += bias[cc];
                if constexpr (CMODE == 0) {
                    float* C = (float*)Cp + (size_t)z * c_zoff;
                    C[rr * ldc + cc] = v;
                } else if constexpr (CMODE == 1) {
                    f16* C = (f16*)Cp + (size_t)z * c_zoff;
                    C[rr * ldc + cc] = (f16)v;
                } else {  // vT[b][col][s]: b = rr>>11, s = rr&2047, col dim 1024
                    f16* C = (f16*)Cp;
                    size_t b = rr >> 11, s = rr & 2047;
                    C[((b << 10) + cc) * 2048 + s] = (f16)v;
                }
            }
        }
    }
}

#define DECL_SMEM                                        \
    __shared__ __align__(16) f16 smem[2 * TILE_ELEMS];   \
    f16* As = smem;                                      \
    f16* Bs = smem + TILE_ELEMS;

// Merged q/k/v projection: z selects input tensor, weight, bias, output mode.
// x = [xq|xk|xv] contiguous, W = [WqT|WkT|WvT] contiguous, qk = [q16|k16] contiguous.
__global__ __launch_bounds__(256, 2) void g_qkv(const f16* x, const f16* W,
                                                f16* qk, f16* vT,
                                                const float* bq, const float* bk,
                                                const float* bv, int D, long long ten) {
    DECL_SMEM
    int z = blockIdx.z;
    const float* bias = (z == 0) ? bq : (z == 1) ? bk : bv;
    if (z < 2) {
        gemm_body<1>(As, Bs, x + (size_t)z * ten, D, 0, W + (size_t)z * D * D, D, 0,
                     qk + (size_t)z * ten, D, 0, bias, D, 0);
    } else {
        gemm_body<3>(As, Bs, x + (size_t)2 * ten, D, 0, W + (size_t)2 * D * D, D, 0,
                     vT, 0, 0, bias, D, 0);
    }
}
__global__ __launch_bounds__(256, 2) void g_scores(const f16* A, int lda, long long az,
                                                   const f16* B, int ldb, long long bz,
                                                   float* C, int ldc, long long cz, int K) {
    DECL_SMEM
    gemm_body<0>(As, Bs, A, lda, az, B, ldb, bz, C, ldc, cz, nullptr, K, blockIdx.z);
}
__global__ __launch_bounds__(256, 2) void g_attnv(const f16* A, int lda, long long az,
                                                  const f16* B, int ldb, long long bz,
                                                  f16* C, int ldc, long long cz, int K) {
    DECL_SMEM
    gemm_body<1>(As, Bs, A, lda, az, B, ldb, bz, C, ldc, cz, nullptr, K, blockIdx.z);
}
__global__ __launch_bounds__(256, 2) void g_out(const f16* A, int lda, const f16* B, int ldb,
                                                float* C, int ldc, const float* bias, int K) {
    DECL_SMEM
    gemm_body<0>(As, Bs, A, lda, 0, B, ldb, 0, C, ldc, 0, bias, K, 0);
}

// Merged preprocessing: fp32->f16 convert of q/k/v AND all four weight
// transposes, one dispatch (1-D grid, decoded). Independent jobs; merging
// removes a dispatch boundary and lets them share BW.
// Blocks [0, 3*CVB): cvt job. Blocks [3*CVB, 3*CVB+4096): wtrans job.
#define CVB 8192  // cvt blocks per tensor: TEN / (256*4) = 8192
__global__ __launch_bounds__(256) void prep(const float* q, const float* k, const float* v,
                                            f16* dst, long long ten,
                                            const float* Wq, const float* Wk,
                                            const float* Wv, const float* Wd,
                                            f16* T, int n) {
    __shared__ float tile[32][33];
    int bid = blockIdx.x;
    if (bid < 3 * CVB) {
        int z = bid >> 13;           // / 8192
        int x = bid & (CVB - 1);
        const float* src = (z == 0) ? q : (z == 1) ? k : v;
        size_t i = ((size_t)x * 256 + threadIdx.x) * 4;
        float4 xv = *(const float4*)(src + i);
        f16x4 h = {(f16)xv.x, (f16)xv.y, (f16)xv.z, (f16)xv.w};
        *(f16x4*)(dst + (size_t)z * ten + i) = h;
    } else {
        int t = bid - 3 * CVB;       // 0..4095
        int z = t >> 10;             // 1024 tile-blocks per matrix (32x32)
        int rem = t & 1023;
        int bx = (rem & 31) * 32;
        int by = (rem >> 5) * 32;
        const float* W = (z == 0) ? Wq : (z == 1) ? Wk : (z == 2) ? Wv : Wd;
        f16* Tz = T + (size_t)z * n * n;
        int tx = threadIdx.x & 31;
        int ty = threadIdx.x >> 5;
        for (int r = ty; r < 32; r += 8) tile[r][tx] = W[(size_t)(by + r) * n + bx + tx];
        __syncthreads();
        for (int r = ty; r < 32; r += 8) Tz[(size_t)(bx + r) * n + by + tx] = (f16)tile[tx][r];
    }
}

// One block per row of 2048 fp32 logits; writes fp16 attn into the first half
// of the same row's storage (row byte stride stays 8192 => f16 lda 4096).
// Vectorized: each thread owns 8 contiguous elements (2x float4 in, 16B out).
// In-place hazard (thread t's f16 writes clobber floats 4t..4t+3, read by
// thread t/2) is ordered by the first __syncthreads: ALL reads happen before it.
__global__ __launch_bounds__(256) void softmax_k(float* scores) {
    size_t row = blockIdx.x;
    float* rp = scores + row * 2048;
    int tid = threadIdx.x;
    int lane = tid & 63, w = tid >> 6;
    const float4* rp4 = (const float4*)(rp + (size_t)tid * 8);
    float4 a = rp4[0], b = rp4[1];
    float x[8] = {a.x, a.y, a.z, a.w, b.x, b.y, b.z, b.w};
    float mx = -3.4e38f;
#pragma unroll
    for (int i = 0; i < 8; ++i) mx = fmaxf(mx, x[i]);
#pragma unroll
    for (int o = 32; o > 0; o >>= 1) mx = fmaxf(mx, __shfl_xor(mx, o, 64));
    __shared__ float redm[4];
    __shared__ float reds[4];
    if (lane == 0) redm[w] = mx;
    __syncthreads();  // also orders: all row reads complete before any write below
    mx = fmaxf(fmaxf(redm[0], redm[1]), fmaxf(redm[2], redm[3]));
    float s = 0.f;
#pragma unroll
    for (int i = 0; i < 8; ++i) {
        x[i] = __expf(x[i] - mx);
        s += x[i];
    }
#pragma unroll
    for (int o = 32; o > 0; o >>= 1) s += __shfl_xor(s, o, 64);
    if (lane == 0) reds[w] = s;
    __syncthreads();
    s = reds[0] + reds[1] + reds[2] + reds[3];
    float inv = 1.f / s;
    f16* op = (f16*)rp + (size_t)tid * 8;
    f16x4 h0 = {(f16)(x[0] * inv), (f16)(x[1] * inv), (f16)(x[2] * inv), (f16)(x[3] * inv)};
    f16x4 h1 = {(f16)(x[4] * inv), (f16)(x[5] * inv), (f16)(x[6] * inv), (f16)(x[7] * inv)};
    *(f16x4*)op = h0;
    *(f16x4*)(op + 4) = h1;
}

extern "C" void kernel_launch(void* const* d_in, const int* in_sizes, int n_in,
                              void* d_out, int out_size, void* d_ws, size_t ws_size,
                              hipStream_t stream) {
    const float* query  = (const float*)d_in[0];
    const float* keys   = (const float*)d_in[1];
    const float* values = (const float*)d_in[2];
    const float* Wq = (const float*)d_in[3];
    const float* bq = (const float*)d_in[4];
    const float* Wk = (const float*)d_in[5];
    const float* bk = (const float*)d_in[6];
    const float* Wv = (const float*)d_in[7];
    const float* bv = (const float*)d_in[8];
    const float* Wd = (const float*)d_in[9];
    const float* bd = (const float*)d_in[10];
    float* out = (float*)d_out;

    const int S = 2048, D = 1024, NB = 4;
    const size_t TEN = (size_t)NB * S * D;  // 8.39M, TEN*2 bytes is 256-aligned

    char* p = (char*)d_ws;
    auto alloc = [&](size_t bytes) {
        char* r = p;
        p += (bytes + 255) & ~(size_t)255;
        return r;
    };
    f16* x3  = (f16*)alloc(TEN * 2 * 3);   // [xq|xk|xv]
    f16* q16 = (f16*)alloc(TEN * 2 * 2);   // [q16|k16]
    f16* k16 = q16 + TEN;
    f16* vT  = (f16*)alloc(TEN * 2);
    f16* WT  = (f16*)alloc((size_t)D * D * 2 * 4);  // [WqT|WkT|WvT|WdT]
    float* scores = (float*)p;
    long long avail = (long long)ws_size - (long long)(p - (char*)d_ws);
    long long sbytes = (long long)S * S * 4;
    int g = (avail >= 4 * sbytes) ? 4 : (avail >= 2 * sbytes) ? 2 : 1;
    f16* att = x3;  // alias: x3 is dead after the qkv projections

    dim3 blk(256);
    prep<<<dim3(3 * CVB + 4096), blk, 0, stream>>>(query, keys, values, x3, (long long)TEN,
                                                   Wq, Wk, Wv, Wd, WT, D);

    g_qkv<<<dim3(D / BN, (NB * S) / BM, 3), blk, 0, stream>>>(
        x3, WT, q16, vT, bq, bk, bv, D, (long long)TEN);

    for (int g0 = 0; g0 < NB; g0 += g) {
        int gz = (NB - g0 < g) ? (NB - g0) : g;
        dim3 sgrid(S / BN, S / BM, gz);  // (16,16,gz)
        g_scores<<<sgrid, blk, 0, stream>>>(
            q16 + (size_t)g0 * S * D, D, (long long)S * D,
            k16 + (size_t)g0 * S * D, D, (long long)S * D,
            scores, S, (long long)S * S, D);
        softmax_k<<<dim3((unsigned)(gz * S)), blk, 0, stream>>>(scores);
        dim3 agrid(D / BN, S / BM, gz);  // (8,16,gz)
        g_attnv<<<agrid, blk, 0, stream>>>(
            (const f16*)scores, 2 * S, (long long)S * 2 * S,
            vT + (size_t)g0 * D * S, S, (long long)D * S,
            att + (size_t)g0 * S * D, D, (long long)S * D, S);
    }

    g_out<<<dim3(D / BN, (NB * S) / BM, 1), blk, 0, stream>>>(att, D, WT + (size_t)3 * D * D, D,
                                                              out, D, bd, D);
}